// Round 5
// baseline (243.976 us; speedup 1.0000x reference)
//
#include <hip/hip_runtime.h>
#include <math.h>

typedef _Float16 h16;
typedef __attribute__((ext_vector_type(8))) _Float16 h16x8;
typedef __attribute__((ext_vector_type(4))) _Float16 h16x4;
typedef __attribute__((ext_vector_type(4))) float f32x4;
typedef unsigned int u32t;

// ---------------------------------------------------------------------------
// k1: fused prep. 64-thread blocks (1 wave), barrier-free streaming GEMMs.
//   blocks 0..3071   : QKV projections (z=bid>>10), 16x64 tile per wave,
//                      A = X f32 (cvt), B = W f32 read strided (no transpose).
//                      z<2 -> qb/kb f16 row-major; z==2 -> vbT transposed.
//   blocks 3072..3263: WbigT[n][s*256+e] = (Wo @ Ws1_s)[e][n]  (f16)
//   blocks 3264..3267: bcomb[j] = bs1[j] + sum_r bo[r&255]*Ws1[r][j]
// ---------------------------------------------------------------------------
__global__ __launch_bounds__(64) void k1_k(
    const float* __restrict__ query, const float* __restrict__ key,
    const float* __restrict__ value,
    const float* __restrict__ Wq, const float* __restrict__ bq,
    const float* __restrict__ Wk, const float* __restrict__ bk,
    const float* __restrict__ Wv, const float* __restrict__ bv,
    const float* __restrict__ Wo, const float* __restrict__ bo,
    const float* __restrict__ Ws1, const float* __restrict__ bs1,
    h16* __restrict__ qb, h16* __restrict__ kb, h16* __restrict__ vbT,
    h16* __restrict__ WbigT, float* __restrict__ bcomb)
{
    const int bid = blockIdx.x, lane = threadIdx.x;
    const int Q = lane >> 4, n = lane & 15;
    const f32x4 z4 = {0.f, 0.f, 0.f, 0.f};

    if (bid < 3072) {                       // ---- QKV ----
        const int z = bid >> 10, tt = bid & 1023;
        const int row0 = (tt & 255) << 4, col0 = (tt >> 8) << 6;
        const float* A    = (z == 0) ? query : (z == 1) ? key : value;
        const float* W    = (z == 0) ? Wq : (z == 1) ? Wk : Wv;
        const float* bias = (z == 0) ? bq : (z == 1) ? bk : bv;

        f32x4 acc[4] = {z4, z4, z4, z4};
        #pragma unroll 2
        for (int k0 = 0; k0 < 256; k0 += 32) {
            const float* ap = A + (size_t)(row0 + n) * 256 + k0 + Q * 8;
            float4 a0 = *(const float4*)ap, a1 = *(const float4*)(ap + 4);
            h16x8 af;
            af[0] = (h16)a0.x; af[1] = (h16)a0.y; af[2] = (h16)a0.z; af[3] = (h16)a0.w;
            af[4] = (h16)a1.x; af[5] = (h16)a1.y; af[6] = (h16)a1.z; af[7] = (h16)a1.w;
            #pragma unroll
            for (int cg = 0; cg < 4; ++cg) {
                const int col = col0 + cg * 16 + n;
                h16x8 bf;
                #pragma unroll
                for (int j = 0; j < 8; ++j)
                    bf[j] = (h16)W[(size_t)(k0 + Q * 8 + j) * 256 + col];
                acc[cg] = __builtin_amdgcn_mfma_f32_16x16x32_f16(af, bf, acc[cg], 0, 0, 0);
            }
        }
        if (z < 2) {
            h16* out = z ? kb : qb;
            #pragma unroll
            for (int cg = 0; cg < 4; ++cg) {
                const int col = col0 + cg * 16 + n;
                const float bvv = bias[col];
                #pragma unroll
                for (int r = 0; r < 4; ++r)
                    out[(size_t)(row0 + 4 * Q + r) * 256 + col] = (h16)(acc[cg][r] + bvv);
            }
        } else {
            const int bb = row0 >> 9, tok0 = (row0 & 511) + 4 * Q;
            #pragma unroll
            for (int cg = 0; cg < 4; ++cg) {
                const int col = col0 + cg * 16 + n;
                const int hh = col >> 5, dd = col & 31;
                const float bvv = bias[col];
                h16x4 pk;
                #pragma unroll
                for (int r = 0; r < 4; ++r) pk[r] = (h16)(acc[cg][r] + bvv);
                *(h16x4*)(vbT + ((size_t)((bb * 8 + hh) * 32 + dd)) * 512 + tok0) = pk;
            }
        }
    } else if (bid < 3264) {                // ---- WbigT ----
        const int idx = bid - 3072;
        const int sgm = idx >> 6, tt = idx & 63;
        const int row0 = (tt & 15) << 4, col0 = (tt >> 4) << 6;
        const float* Bsrc = Ws1 + (size_t)sgm * 65536;

        f32x4 acc[4] = {z4, z4, z4, z4};
        #pragma unroll 2
        for (int k0 = 0; k0 < 256; k0 += 32) {
            const float* ap = Wo + (size_t)(row0 + n) * 256 + k0 + Q * 8;
            float4 a0 = *(const float4*)ap, a1 = *(const float4*)(ap + 4);
            h16x8 af;
            af[0] = (h16)a0.x; af[1] = (h16)a0.y; af[2] = (h16)a0.z; af[3] = (h16)a0.w;
            af[4] = (h16)a1.x; af[5] = (h16)a1.y; af[6] = (h16)a1.z; af[7] = (h16)a1.w;
            #pragma unroll
            for (int cg = 0; cg < 4; ++cg) {
                const int col = col0 + cg * 16 + n;
                h16x8 bf;
                #pragma unroll
                for (int j = 0; j < 8; ++j)
                    bf[j] = (h16)Bsrc[(size_t)(k0 + Q * 8 + j) * 256 + col];
                acc[cg] = __builtin_amdgcn_mfma_f32_16x16x32_f16(af, bf, acc[cg], 0, 0, 0);
            }
        }
        #pragma unroll
        for (int cg = 0; cg < 4; ++cg) {
            const int col = col0 + cg * 16 + n;
            h16x4 pk;
            #pragma unroll
            for (int r = 0; r < 4; ++r) pk[r] = (h16)acc[cg][r];
            *(h16x4*)(WbigT + (size_t)col * 768 + sgm * 256 + row0 + 4 * Q) = pk;
        }
    } else {                                // ---- bcomb ----
        const int col = ((bid - 3264) << 6) + lane;
        float acc = bs1[col];
        #pragma unroll 16
        for (int r = 0; r < 768; ++r)
            acc = fmaf(bo[r & 255], Ws1[(size_t)r * 256 + col], acc);
        bcomb[col] = acc;
    }
}

// ---------------------------------------------------------------------------
// attn: MFMA flash attention, 3 nested scales, ONE online max. Block =
// (b, 16 q) x 4 heads, but waves are fully independent: NO __syncthreads.
// Each wave computes its own head's f_h(d) inline in A-layout (contiguous
// 16B d/mask loads). Mask folded into sv=-3e38. Per-wave Sx double-buffered
// (stride 76 -> <=2-way banks) for the C->A layout transpose of raw scores.
// Depth-1 register prefetch of all global loads.
// ---------------------------------------------------------------------------
__global__ __launch_bounds__(256, 2) void attn_k(
    const h16* __restrict__ qb, const h16* __restrict__ kb,
    const h16* __restrict__ vbT,
    const float* __restrict__ dist, const int* __restrict__ mask,
    const float* __restrict__ cw1, const float* __restrict__ cb1,
    const float* __restrict__ cw2, const float* __restrict__ cb2,
    h16* __restrict__ OB)
{
    const int bx = blockIdx.x, b = bx >> 5, q0 = (bx & 31) * 16;
    const int hg = blockIdx.y;
    const int t = threadIdx.x, w = t >> 6, lane = t & 63;
    const int Q = lane >> 4, n = lane & 15;
    const int h = hg * 4 + w;

    __shared__ __align__(16) h16 Sx[4][2][16][76];

    const float invs = 0.17677669529663687f;   // 1/sqrt(32)
    float w1[8], b1[8], w2w[8];
    #pragma unroll
    for (int u = 0; u < 8; ++u) {
        w1[u] = cw1[u]; b1[u] = cb1[u];
        w2w[u] = invs * cw2[h * 8 + u];
    }
    const float fb = invs * cb2[h];

    const h16x8 aq =
        *(const h16x8*)(qb + ((size_t)(b * 512 + q0 + n)) * 256 + h * 32 + Q * 8);

    const f32x4 z4 = {0.f, 0.f, 0.f, 0.f};
    f32x4 acc[3][2];
    #pragma unroll
    for (int s = 0; s < 3; ++s) { acc[s][0] = z4; acc[s][1] = z4; }
    float mprev = -3e38f, lsum[3] = {0.f, 0.f, 0.f};

    const size_t dmrow = ((size_t)(b * 512 + q0 + n)) * 512 + Q * 8;
    const size_t kbase = ((size_t)(b * 512)) * 256 + h * 32 + Q * 8;
    const size_t vbase = ((size_t)((b * 8 + h) * 32 + n)) * 512 + Q * 8;
    const bool qz = (q0 + n) == 0;

    // ---- chunk-0 loads ----
    h16x8 kf[4], vf[4];
    float4 df[4]; int4 mf[4];
    #pragma unroll
    for (int cg = 0; cg < 4; ++cg)
        kf[cg] = *(const h16x8*)(kb + kbase + (size_t)(cg * 16 + n) * 256);
    #pragma unroll
    for (int nh = 0; nh < 2; ++nh)
        #pragma unroll
        for (int k2 = 0; k2 < 2; ++k2)
            vf[nh * 2 + k2] = *(const h16x8*)(vbT + vbase + nh * 16 * 512 + k2 * 32);
    df[0] = *(const float4*)(dist + dmrow);
    df[1] = *(const float4*)(dist + dmrow + 4);
    df[2] = *(const float4*)(dist + dmrow + 32);
    df[3] = *(const float4*)(dist + dmrow + 36);
    mf[0] = *(const int4*)(mask + dmrow);
    mf[1] = *(const int4*)(mask + dmrow + 4);
    mf[2] = *(const int4*)(mask + dmrow + 32);
    mf[3] = *(const int4*)(mask + dmrow + 36);

    #pragma unroll 1
    for (int kc = 0; kc < 8; ++kc) {
        const int kk0 = kc * 64, cb_ = kc & 1;

        // ---- prefetch chunk kc+1 ----
        h16x8 kfN[4], vfN[4]; float4 dfN[4]; int4 mfN[4];
        if (kc < 7) {
            const int kn = kk0 + 64;
            #pragma unroll
            for (int cg = 0; cg < 4; ++cg)
                kfN[cg] = *(const h16x8*)(kb + kbase + (size_t)(kn + cg * 16 + n) * 256);
            #pragma unroll
            for (int nh = 0; nh < 2; ++nh)
                #pragma unroll
                for (int k2 = 0; k2 < 2; ++k2)
                    vfN[nh * 2 + k2] =
                        *(const h16x8*)(vbT + vbase + nh * 16 * 512 + kn + k2 * 32);
            dfN[0] = *(const float4*)(dist + dmrow + kn);
            dfN[1] = *(const float4*)(dist + dmrow + kn + 4);
            dfN[2] = *(const float4*)(dist + dmrow + kn + 32);
            dfN[3] = *(const float4*)(dist + dmrow + kn + 36);
            mfN[0] = *(const int4*)(mask + dmrow + kn);
            mfN[1] = *(const int4*)(mask + dmrow + kn + 4);
            mfN[2] = *(const int4*)(mask + dmrow + kn + 32);
            mfN[3] = *(const int4*)(mask + dmrow + kn + 36);
        }

        // ---- QK^T, write raw S transposed (per-wave) ----
        f32x4 s4[4];
        #pragma unroll
        for (int cg = 0; cg < 4; ++cg)
            s4[cg] = __builtin_amdgcn_mfma_f32_16x16x32_f16(aq, kf[cg], z4, 0, 0, 0);
        #pragma unroll
        for (int cg = 0; cg < 4; ++cg)
            #pragma unroll
            for (int r = 0; r < 4; ++r)
                Sx[w][cb_][4 * Q + r][cg * 16 + n] = (h16)s4[cg][r];
        __builtin_amdgcn_wave_barrier();
        const h16x8 sh0 = *(const h16x8*)&Sx[w][cb_][n][Q * 8];
        const h16x8 sh1 = *(const h16x8*)&Sx[w][cb_][n][32 + Q * 8];
        __builtin_amdgcn_wave_barrier();

        // ---- A-layout: f_h(d), mask, running max ----
        float sv[16]; bool in0[16], in1[16];
        float cm = -3e38f;
        #pragma unroll
        for (int i = 0; i < 16; ++i) {
            const float d = ((i & 8) ? df[2 + ((i >> 2) & 1)] : df[(i >> 2) & 1])[i & 3];
            const int  mk = ((i & 8) ? mf[2 + ((i >> 2) & 1)] : mf[(i >> 2) & 1])[i & 3];
            float f = fb;
            #pragma unroll
            for (int u = 0; u < 8; ++u)
                f = fmaf(fmaxf(fmaf(d, w1[u], b1[u]), 0.f), w2w[u], f);
            const float sraw = (float)((i < 8) ? sh0[i] : sh1[i & 7]);
            const int kg = kk0 + ((i < 8) ? (Q * 8 + i) : (32 + Q * 8 + (i & 7)));
            const bool fr = qz || (kg == 0);
            const float s = (mk != 0) ? sraw * f : -3e38f;
            sv[i] = s;
            in0[i] = fr || (d < 0.3f);
            in1[i] = fr || (d < 0.7f);
            cm = fmaxf(cm, s);
        }
        cm = fmaxf(cm, __shfl_xor(cm, 16));
        cm = fmaxf(cm, __shfl_xor(cm, 32));
        const float mnew = fmaxf(mprev, cm);
        const float alphaA = __expf(mprev - mnew);
        mprev = mnew;

        #pragma unroll
        for (int r = 0; r < 4; ++r) {
            const float aR = __shfl(alphaA, 4 * Q + r);
            #pragma unroll
            for (int s = 0; s < 3; ++s) { acc[s][0][r] *= aR; acc[s][1][r] *= aR; }
        }

        // ---- exp + PV, one k-half at a time ----
        float l0 = 0.f, l1 = 0.f, l2 = 0.f;
        #pragma unroll
        for (int k2 = 0; k2 < 2; ++k2) {
            h16x8 pf0, pf1, pf2;
            #pragma unroll
            for (int j = 0; j < 8; ++j) {
                const int i = k2 * 8 + j;
                const float e = __expf(sv[i] - mnew);
                const float p0 = in0[i] ? e : 0.f;
                const float p1 = in1[i] ? e : 0.f;
                l0 += p0; l1 += p1; l2 += e;
                pf0[j] = (h16)p0; pf1[j] = (h16)p1; pf2[j] = (h16)e;
            }
            #pragma unroll
            for (int nh = 0; nh < 2; ++nh) {
                acc[0][nh] = __builtin_amdgcn_mfma_f32_16x16x32_f16(
                    pf0, vf[nh * 2 + k2], acc[0][nh], 0, 0, 0);
                acc[1][nh] = __builtin_amdgcn_mfma_f32_16x16x32_f16(
                    pf1, vf[nh * 2 + k2], acc[1][nh], 0, 0, 0);
                acc[2][nh] = __builtin_amdgcn_mfma_f32_16x16x32_f16(
                    pf2, vf[nh * 2 + k2], acc[2][nh], 0, 0, 0);
            }
        }
        lsum[0] = lsum[0] * alphaA + l0;
        lsum[1] = lsum[1] * alphaA + l1;
        lsum[2] = lsum[2] * alphaA + l2;

        if (kc < 7) {
            #pragma unroll
            for (int i = 0; i < 4; ++i) {
                kf[i] = kfN[i]; vf[i] = vfN[i]; df[i] = dfN[i]; mf[i] = mfN[i];
            }
        }
    }

    // ---- epilogue ----
    float lrow[3];
    #pragma unroll
    for (int s = 0; s < 3; ++s) {
        float lv = lsum[s];
        lv += __shfl_xor(lv, 16);
        lv += __shfl_xor(lv, 32);
        lrow[s] = lv;
    }
    #pragma unroll
    for (int s = 0; s < 3; ++s) {
        #pragma unroll
        for (int r = 0; r < 4; ++r) {
            const float il = 1.0f / __shfl(lrow[s], 4 * Q + r);
            const size_t row = (size_t)(b * 512 + q0 + 4 * Q + r);
            h16* op = OB + row * 768 + s * 256 + h * 32 + n;
            op[0]  = (h16)(acc[s][0][r] * il);
            op[16] = (h16)(acc[s][1][r] * il);
        }
    }
}

// ---------------------------------------------------------------------------
// g1: h1 = relu(OB @ WbigT^T + bcomb), f16 in/out. Streaming 16x64/wave.
// ---------------------------------------------------------------------------
__global__ __launch_bounds__(64) void g1_k(
    const h16* __restrict__ OB, const h16* __restrict__ WbigT,
    const float* __restrict__ bcomb, h16* __restrict__ h1)
{
    const int lane = threadIdx.x, Q = lane >> 4, n = lane & 15;
    const int row0 = (blockIdx.x & 255) << 4, col0 = (blockIdx.x >> 8) << 6;
    const f32x4 z4 = {0.f, 0.f, 0.f, 0.f};
    f32x4 acc[4] = {z4, z4, z4, z4};

    #pragma unroll 4
    for (int k0 = 0; k0 < 768; k0 += 32) {
        h16x8 af = *(const h16x8*)(OB + (size_t)(row0 + n) * 768 + k0 + Q * 8);
        #pragma unroll
        for (int cg = 0; cg < 4; ++cg) {
            h16x8 bf = *(const h16x8*)(WbigT + (size_t)(col0 + cg * 16 + n) * 768 + k0 + Q * 8);
            acc[cg] = __builtin_amdgcn_mfma_f32_16x16x32_f16(af, bf, acc[cg], 0, 0, 0);
        }
    }
    #pragma unroll
    for (int cg = 0; cg < 4; ++cg) {
        const int col = col0 + cg * 16 + n;
        const float bvv = bcomb[col];
        #pragma unroll
        for (int r = 0; r < 4; ++r)
            h1[(size_t)(row0 + 4 * Q + r) * 256 + col] = (h16)fmaxf(acc[cg][r] + bvv, 0.f);
    }
}

// ---------------------------------------------------------------------------
// g2: out(f32) = h1 @ Ws2 + bs2. B read strided from f32 Ws2 directly.
// ---------------------------------------------------------------------------
__global__ __launch_bounds__(64) void g2_k(
    const h16* __restrict__ h1, const float* __restrict__ Ws2,
    const float* __restrict__ bs2, float* __restrict__ out)
{
    const int lane = threadIdx.x, Q = lane >> 4, n = lane & 15;
    const int row0 = (blockIdx.x & 255) << 4, col0 = (blockIdx.x >> 8) << 6;
    const f32x4 z4 = {0.f, 0.f, 0.f, 0.f};
    f32x4 acc[4] = {z4, z4, z4, z4};

    #pragma unroll 2
    for (int k0 = 0; k0 < 256; k0 += 32) {
        h16x8 af = *(const h16x8*)(h1 + (size_t)(row0 + n) * 256 + k0 + Q * 8);
        #pragma unroll
        for (int cg = 0; cg < 4; ++cg) {
            const int col = col0 + cg * 16 + n;
            h16x8 bf;
            #pragma unroll
            for (int j = 0; j < 8; ++j)
                bf[j] = (h16)Ws2[(size_t)(k0 + Q * 8 + j) * 256 + col];
            acc[cg] = __builtin_amdgcn_mfma_f32_16x16x32_f16(af, bf, acc[cg], 0, 0, 0);
        }
    }
    #pragma unroll
    for (int cg = 0; cg < 4; ++cg) {
        const int col = col0 + cg * 16 + n;
        const float bvv = bs2[col];
        #pragma unroll
        for (int r = 0; r < 4; ++r)
            out[(size_t)(row0 + 4 * Q + r) * 256 + col] = acc[cg][r] + bvv;
    }
}

// ---------------------------------------------------------------------------
extern "C" void kernel_launch(void* const* d_in, const int* in_sizes, int n_in,
                              void* d_out, int out_size, void* d_ws, size_t ws_size,
                              hipStream_t stream)
{
    const float* query = (const float*)d_in[0];
    const float* key   = (const float*)d_in[1];
    const float* value = (const float*)d_in[2];
    const float* dist  = (const float*)d_in[3];
    const int*   mask  = (const int*)d_in[4];
    const float* Wq = (const float*)d_in[5];  const float* bq = (const float*)d_in[6];
    const float* Wk = (const float*)d_in[7];  const float* bk = (const float*)d_in[8];
    const float* Wv = (const float*)d_in[9];  const float* bv = (const float*)d_in[10];
    const float* Wo = (const float*)d_in[11]; const float* bo = (const float*)d_in[12];
    const float* cw1 = (const float*)d_in[13]; const float* cb1 = (const float*)d_in[14];
    const float* cw2 = (const float*)d_in[15]; const float* cb2 = (const float*)d_in[16];
    const float* Ws1 = (const float*)d_in[17]; const float* bs1 = (const float*)d_in[18];
    const float* Ws2 = (const float*)d_in[19]; const float* bs2 = (const float*)d_in[20];

    h16* qb    = (h16*)d_ws;            // 4096x256
    h16* kb    = qb + 1048576;          // 4096x256
    h16* vbT   = kb + 1048576;          // 64x32 x 512
    h16* OB    = vbT + 1048576;         // 4096x768
    h16* h1    = OB + 3145728;          // 4096x256
    h16* WbigT = h1 + 1048576;          // 256 x 768
    float* bcomb = (float*)(WbigT + 196608);  // 256

    k1_k<<<dim3(3268), 64, 0, stream>>>(query, key, value, Wq, bq, Wk, bk,
                                        Wv, bv, Wo, bo, Ws1, bs1,
                                        qb, kb, vbT, WbigT, bcomb);

    attn_k<<<dim3(256, 2), 256, 0, stream>>>(qb, kb, vbT, dist, mask,
                                             cw1, cb1, cw2, cb2, OB);

    g1_k<<<dim3(1024), 64, 0, stream>>>(OB, WbigT, bcomb, h1);
    g2_k<<<dim3(1024), 64, 0, stream>>>(h1, Ws2, bs2, (float*)d_out);
}

// Round 6
// 191.854 us; speedup vs baseline: 1.2717x; 1.2717x over previous
//
#include <hip/hip_runtime.h>
#include <math.h>

typedef _Float16 h16;
typedef __attribute__((ext_vector_type(8))) _Float16 h16x8;
typedef __attribute__((ext_vector_type(4))) _Float16 h16x4;
typedef __attribute__((ext_vector_type(4))) float f32x4;
typedef unsigned long long u64t;
typedef unsigned int u32t;
typedef unsigned short u16t;

// ---------------------------------------------------------------------------
// k1: one fused prep launch, 256-thr blocks, grid 1905:
//   0..767   : QKV projections, 64x64 staged tiles, on-the-fly B transpose
//   768..815 : WbigT[j][s*256+i] = (Wo @ Ws1_s)[i][j]  (48 blocks)
//   816..879 : Ws2T transpose f32->f16 (64 blocks)
//   880      : bcomb[j] = bs1[j] + sum_r bo[r&255]*Ws1[r][j]
//   881..1904: fB[b,h,q,k] = f16(invs*f_h(dist)) with 3 code bits in LSBs
// ---------------------------------------------------------------------------
__global__ __launch_bounds__(256) void k1_k(
    const float* __restrict__ query, const float* __restrict__ key,
    const float* __restrict__ value,
    const float* __restrict__ Wq, const float* __restrict__ bq,
    const float* __restrict__ Wk, const float* __restrict__ bk,
    const float* __restrict__ Wv, const float* __restrict__ bv,
    const float* __restrict__ Wo, const float* __restrict__ bo,
    const float* __restrict__ cw1, const float* __restrict__ cb1,
    const float* __restrict__ cw2, const float* __restrict__ cb2,
    const float* __restrict__ Ws1, const float* __restrict__ bs1,
    const float* __restrict__ Ws2, const float* __restrict__ dist,
    const int* __restrict__ mask,
    h16* __restrict__ qb, h16* __restrict__ kb, h16* __restrict__ vbT,
    h16* __restrict__ WbigT, h16* __restrict__ Ws2T,
    u16t* __restrict__ fB, float* __restrict__ bcomb)
{
    const int bid = blockIdx.x, t = threadIdx.x;
    const f32x4 z4 = {0.f, 0.f, 0.f, 0.f};

    if (bid < 816) {                       // ======== staged 64x64 GEMMs ========
        int z, row0, col0, sgm = 0;
        const float *A, *Bsrc, *bias = nullptr;
        if (bid < 768) {
            z = bid >> 8; const int idx = bid & 255;
            row0 = (idx & 63) * 64; col0 = (idx >> 6) * 64;
            A    = (z == 0) ? query : (z == 1) ? key : value;
            Bsrc = (z == 0) ? Wq : (z == 1) ? Wk : Wv;
            bias = (z == 0) ? bq : (z == 1) ? bk : bv;
        } else {
            z = 3; const int idx = bid - 768;
            sgm = idx >> 4; const int tt = idx & 15;
            row0 = (tt & 3) * 64; col0 = (tt >> 2) * 64;
            A = Wo; Bsrc = Ws1 + (size_t)sgm * 65536;
        }
        __shared__ __align__(16) h16 As[64][40];
        __shared__ __align__(16) u32t Bs[64][20];
        const int w = t >> 6, lane = t & 63, Q = lane >> 4, n = lane & 15;
        const int sr = t >> 2, sc = (t & 3) * 8;     // A staging
        const int kk2 = t & 15, cs4 = (t >> 4) * 4;  // B transpose staging
        f32x4 acc[4] = {z4, z4, z4, z4};

        for (int k0 = 0; k0 < 256; k0 += 32) {
            __syncthreads();
            {   // A: f32 -> f16
                const float* ap = A + (size_t)(row0 + sr) * 256 + k0 + sc;
                float4 a0 = *(const float4*)ap, a1 = *(const float4*)(ap + 4);
                h16x8 hv;
                hv[0] = (h16)a0.x; hv[1] = (h16)a0.y; hv[2] = (h16)a0.z; hv[3] = (h16)a0.w;
                hv[4] = (h16)a1.x; hv[5] = (h16)a1.y; hv[6] = (h16)a1.z; hv[7] = (h16)a1.w;
                *(h16x8*)&As[sr][sc] = hv;
                // B: transpose-stage W[k][col] -> Bs[col][k] (u32 = k-pair)
                const float* b0p = Bsrc + (size_t)(k0 + 2 * kk2) * 256 + col0 + cs4;
                float4 r0 = *(const float4*)b0p;
                float4 r1 = *(const float4*)(b0p + 256);
                const float lo[4] = {r0.x, r0.y, r0.z, r0.w};
                const float hi[4] = {r1.x, r1.y, r1.z, r1.w};
                #pragma unroll
                for (int j = 0; j < 4; ++j) {
                    union { h16 h[2]; u32t u; } pk;
                    pk.h[0] = (h16)lo[j]; pk.h[1] = (h16)hi[j];
                    Bs[cs4 + j][kk2] = pk.u;
                }
            }
            __syncthreads();
            h16x8 af = *(const h16x8*)&As[w * 16 + n][Q * 8];
            #pragma unroll
            for (int cg = 0; cg < 4; ++cg) {
                h16x8 bf = *(const h16x8*)&Bs[cg * 16 + n][4 * Q];
                acc[cg] = __builtin_amdgcn_mfma_f32_16x16x32_f16(af, bf, acc[cg], 0, 0, 0);
            }
        }

        if (z < 2) {
            h16* out = z ? kb : qb;
            #pragma unroll
            for (int cg = 0; cg < 4; ++cg) {
                const int col = col0 + cg * 16 + n;
                const float bvv = bias[col];
                #pragma unroll
                for (int r = 0; r < 4; ++r)
                    out[(size_t)(row0 + w * 16 + 4 * Q + r) * 256 + col] =
                        (h16)(acc[cg][r] + bvv);
            }
        } else if (z == 2) {
            const int bb = row0 >> 9, tok0 = (row0 & 511) + w * 16 + 4 * Q;
            #pragma unroll
            for (int cg = 0; cg < 4; ++cg) {
                const int col = col0 + cg * 16 + n;
                const float bvv = bias[col];
                h16x4 pk;
                #pragma unroll
                for (int r = 0; r < 4; ++r) pk[r] = (h16)(acc[cg][r] + bvv);
                *(h16x4*)(vbT + ((size_t)((bb * 8 + (col >> 5)) * 32 + (col & 31))) * 512
                              + tok0) = pk;
            }
        } else {
            #pragma unroll
            for (int cg = 0; cg < 4; ++cg) {
                const int col = col0 + cg * 16 + n;
                h16x4 pk;
                #pragma unroll
                for (int r = 0; r < 4; ++r) pk[r] = (h16)acc[cg][r];
                *(h16x4*)(WbigT + (size_t)col * 768 + sgm * 256 + row0 + w * 16 + 4 * Q) = pk;
            }
        }
    } else if (bid < 880) {                // ======== Ws2T transpose ========
        const int idx = bid - 816;
        const int r0 = (idx >> 3) * 32, c0 = (idx & 7) * 32;
        __shared__ float T[32][33];
        const int tx = t & 31, ty = t >> 5;
        #pragma unroll
        for (int i = 0; i < 4; ++i)
            T[ty + i * 8][tx] = Ws2[(size_t)(r0 + ty + i * 8) * 256 + c0 + tx];
        __syncthreads();
        #pragma unroll
        for (int i = 0; i < 4; ++i)
            Ws2T[(size_t)(c0 + ty + i * 8) * 256 + r0 + tx] = (h16)T[tx][ty + i * 8];
    } else if (bid == 880) {               // ======== bcomb ========
        float acc = bs1[t];
        for (int r = 0; r < 768; ++r)
            acc = fmaf(bo[r & 255], Ws1[(size_t)r * 256 + t], acc);
        bcomb[t] = acc;
    } else {                               // ======== fB precompute ========
        const int idx = (bid - 881) * 256 + t;
        const int b = idx >> 15, q = (idx >> 6) & 511, k8 = (idx & 63) << 3;
        const size_t dm = ((size_t)(b * 512 + q)) * 512 + k8;
        float4 d0 = *(const float4*)(dist + dm), d1 = *(const float4*)(dist + dm + 4);
        int4 m0 = *(const int4*)(mask + dm),  m1 = *(const int4*)(mask + dm + 4);
        const float dd[8] = {d0.x, d0.y, d0.z, d0.w, d1.x, d1.y, d1.z, d1.w};
        const int   mm[8] = {m0.x, m0.y, m0.z, m0.w, m1.x, m1.y, m1.z, m1.w};
        const float invs = 0.17677669529663687f;
        float w1v[8], b1v[8], fb0[8], w2v[8][8];
        #pragma unroll
        for (int u = 0; u < 8; ++u) { w1v[u] = cw1[u]; b1v[u] = cb1[u]; }
        #pragma unroll
        for (int hh = 0; hh < 8; ++hh) {
            fb0[hh] = invs * cb2[hh];
            #pragma unroll
            for (int u = 0; u < 8; ++u) w2v[hh][u] = invs * cw2[hh * 8 + u];
        }
        u32t outw[8][4] = {};
        #pragma unroll
        for (int j = 0; j < 8; ++j) {
            float ru[8];
            #pragma unroll
            for (int u = 0; u < 8; ++u) ru[u] = fmaxf(fmaf(dd[j], w1v[u], b1v[u]), 0.f);
            const bool fr = (q == 0) || ((k8 + j) == 0);
            const u32t code = ((fr || dd[j] < 0.3f) ? 1u : 0u)
                            | ((fr || dd[j] < 0.7f) ? 2u : 0u)
                            | ((mm[j] != 0) ? 4u : 0u);
            #pragma unroll
            for (int hh = 0; hh < 8; ++hh) {
                float f = fb0[hh];
                #pragma unroll
                for (int u = 0; u < 8; ++u) f = fmaf(ru[u], w2v[hh][u], f);
                union { h16 hv; u16t us; } cv; cv.hv = (h16)f;
                const u32t bits = ((u32t)cv.us & 0xFFF8u) | code;
                outw[hh][j >> 1] |= bits << (16 * (j & 1));
            }
        }
        #pragma unroll
        for (int hh = 0; hh < 8; ++hh) {
            u16t* fp = fB + ((size_t)((b * 8 + hh) * 512 + q)) * 512 + k8;
            *(uint4*)fp = make_uint4(outw[hh][0], outw[hh][1], outw[hh][2], outw[hh][3]);
        }
    }
}

// ---------------------------------------------------------------------------
// attn: 1 wave per block (64 thr), grid 2048 = (b,h) x 32 q-tiles of 16.
// ZERO LDS, zero barriers. S^T = mfma(K-frag, Q-frag) leaves S[q=n][k] in-lane;
// PV uses the permuted k-order k~(Q,j)=16(j>>2)+4Q+(j&3) so P is the A-frag
// with no data movement; V B-frags are loaded at matching permuted addresses.
// f_h(d)+codes read from precomputed fB (3 LSB code bits). One online max
// (scale sets nested). kf/f depth-1 prefetch; no launch-bounds VGPR cap.
// ---------------------------------------------------------------------------
__global__ __launch_bounds__(64) void attn_k(
    const h16* __restrict__ qb, const h16* __restrict__ kb,
    const h16* __restrict__ vbT, const u16t* __restrict__ fB,
    h16* __restrict__ OB)
{
    const int bid = blockIdx.x;
    const int bh = bid >> 5, qt = bid & 31;
    const int b = bh >> 3, h = bh & 7;
    const int q0 = qt * 16;
    const int lane = threadIdx.x, Q = lane >> 4, n = lane & 15;

    const h16x8 aq =
        *(const h16x8*)(qb + ((size_t)(b * 512 + q0 + n)) * 256 + h * 32 + Q * 8);

    const f32x4 z4 = {0.f, 0.f, 0.f, 0.f};
    f32x4 acc[3][2];
    #pragma unroll
    for (int s = 0; s < 3; ++s) { acc[s][0] = z4; acc[s][1] = z4; }
    float mprev = -3e38f, lsum[3] = {0.f, 0.f, 0.f};

    const size_t kbase = (size_t)(b * 512) * 256 + h * 32 + Q * 8;
    const size_t fbase = ((size_t)(bh * 512 + q0 + n)) * 512;
    const size_t vrow0 = ((size_t)(bh * 32 + n)) * 512;
    const size_t vrow1 = ((size_t)(bh * 32 + 16 + n)) * 512;

    h16x8 kf[4]; u64t fw[4];
    #pragma unroll
    for (int cg = 0; cg < 4; ++cg) {
        kf[cg] = *(const h16x8*)(kb + kbase + (size_t)(cg * 16 + n) * 256);
        fw[cg] = *(const u64t*)(fB + fbase + cg * 16 + 4 * Q);
    }

    #pragma unroll 1
    for (int kc = 0; kc < 8; ++kc) {
        const int kk0 = kc * 64;

        // V B-frags for this chunk (consumed late -> latency hidden)
        h16x4 vf[2][2][2];    // [k2][nh][jg]
        #pragma unroll
        for (int k2 = 0; k2 < 2; ++k2)
            #pragma unroll
            for (int jg = 0; jg < 2; ++jg) {
                const int off = kk0 + k2 * 32 + jg * 16 + 4 * Q;
                vf[k2][0][jg] = *(const h16x4*)(vbT + vrow0 + off);
                vf[k2][1][jg] = *(const h16x4*)(vbT + vrow1 + off);
            }

        // S^T = K . Q^T  (C rows = local k = 4Q+r, cols = q = n)
        f32x4 s4t[4];
        #pragma unroll
        for (int cg = 0; cg < 4; ++cg)
            s4t[cg] = __builtin_amdgcn_mfma_f32_16x16x32_f16(kf[cg], aq, z4, 0, 0, 0);

        // prefetch next chunk's K-frags + f-words
        h16x8 kfN[4]; u64t fwN[4];
        if (kc < 7) {
            #pragma unroll
            for (int cg = 0; cg < 4; ++cg) {
                kfN[cg] = *(const h16x8*)(kb + kbase + (size_t)(kk0 + 64 + cg * 16 + n) * 256);
                fwN[cg] = *(const u64t*)(fB + fbase + kk0 + 64 + cg * 16 + 4 * Q);
            }
        }

        // decode f/codes, scale, single online max
        float sv[16]; u32t bm0 = 0, bm1 = 0;
        float cm = -3e38f;
        #pragma unroll
        for (int cg = 0; cg < 4; ++cg)
            #pragma unroll
            for (int r = 0; r < 4; ++r) {
                const u32t u = (u32t)(fw[cg] >> (16 * r)) & 0xFFFFu;
                union { u16t us; h16 hv; } cv; cv.us = (u16t)(u & 0xFFF8u);
                const float s = (u & 4u) ? s4t[cg][r] * (float)cv.hv : -3e38f;
                const int i = cg * 4 + r;
                sv[i] = s;
                bm0 |= (u & 1u) << i;
                bm1 |= ((u >> 1) & 1u) << i;
                cm = fmaxf(cm, s);
            }
        cm = fmaxf(cm, __shfl_xor(cm, 16));
        cm = fmaxf(cm, __shfl_xor(cm, 32));
        const float mnew = fmaxf(mprev, cm);
        const float alpha = __expf(mprev - mnew);
        mprev = mnew;

        // rescale acc rows (row q = 4Q+r needs alpha of lane 4Q+r)
        #pragma unroll
        for (int r = 0; r < 4; ++r) {
            const float aR = __shfl(alpha, 4 * Q + r);
            #pragma unroll
            for (int s = 0; s < 3; ++s) { acc[s][0][r] *= aR; acc[s][1][r] *= aR; }
        }

        // exp + P fragments (in-lane, permuted k-order) + PV
        float E[16];
        float l0 = 0.f, l1 = 0.f, l2 = 0.f;
        #pragma unroll
        for (int i = 0; i < 16; ++i) {
            const float e = __expf(sv[i] - mnew);
            E[i] = e;
            l2 += e;
            l0 += ((bm0 >> i) & 1u) ? e : 0.f;
            l1 += ((bm1 >> i) & 1u) ? e : 0.f;
        }
        #pragma unroll
        for (int k2 = 0; k2 < 2; ++k2) {
            h16x8 pf0, pf1, pf2;
            #pragma unroll
            for (int j = 0; j < 8; ++j) {
                const int i = (2 * k2 + (j >> 2)) * 4 + (j & 3);
                const float e = E[i];
                pf0[j] = (h16)(((bm0 >> i) & 1u) ? e : 0.f);
                pf1[j] = (h16)(((bm1 >> i) & 1u) ? e : 0.f);
                pf2[j] = (h16)e;
            }
            #pragma unroll
            for (int nh = 0; nh < 2; ++nh) {
                union { h16x4 h4[2]; h16x8 h8; } vv;
                vv.h4[0] = vf[k2][nh][0]; vv.h4[1] = vf[k2][nh][1];
                acc[0][nh] = __builtin_amdgcn_mfma_f32_16x16x32_f16(pf0, vv.h8, acc[0][nh], 0, 0, 0);
                acc[1][nh] = __builtin_amdgcn_mfma_f32_16x16x32_f16(pf1, vv.h8, acc[1][nh], 0, 0, 0);
                acc[2][nh] = __builtin_amdgcn_mfma_f32_16x16x32_f16(pf2, vv.h8, acc[2][nh], 0, 0, 0);
            }
        }
        lsum[0] = lsum[0] * alpha + l0;
        lsum[1] = lsum[1] * alpha + l1;
        lsum[2] = lsum[2] * alpha + l2;

        if (kc < 7) {
            #pragma unroll
            for (int cg = 0; cg < 4; ++cg) { kf[cg] = kfN[cg]; fw[cg] = fwN[cg]; }
        }
    }

    // epilogue
    float lrow[3];
    #pragma unroll
    for (int s = 0; s < 3; ++s) {
        float lv = lsum[s];
        lv += __shfl_xor(lv, 16);
        lv += __shfl_xor(lv, 32);
        lrow[s] = lv;
    }
    #pragma unroll
    for (int s = 0; s < 3; ++s)
        #pragma unroll
        for (int r = 0; r < 4; ++r) {
            const float il = 1.0f / __shfl(lrow[s], 4 * Q + r);
            h16* op = OB + (size_t)(b * 512 + q0 + 4 * Q + r) * 768 + s * 256 + h * 32 + n;
            op[0]  = (h16)(acc[s][0][r] * il);
            op[16] = (h16)(acc[s][1][r] * il);
        }
}

// ---------------------------------------------------------------------------
// g1: h1 = relu(OB @ WbigT^T + bcomb). 1 wave/block, 16x32 tile, grid 2048.
// ---------------------------------------------------------------------------
__global__ __launch_bounds__(64) void g1_k(
    const h16* __restrict__ OB, const h16* __restrict__ WbigT,
    const float* __restrict__ bcomb, h16* __restrict__ h1)
{
    const int lane = threadIdx.x, Q = lane >> 4, n = lane & 15;
    const int row0 = (blockIdx.x >> 3) * 16, col0 = (blockIdx.x & 7) * 32;
    const f32x4 z4 = {0.f, 0.f, 0.f, 0.f};
    f32x4 acc[2] = {z4, z4};
    #pragma unroll 4
    for (int k0 = 0; k0 < 768; k0 += 32) {
        h16x8 af = *(const h16x8*)(OB + (size_t)(row0 + n) * 768 + k0 + Q * 8);
        #pragma unroll
        for (int c = 0; c < 2; ++c) {
            h16x8 bf = *(const h16x8*)(WbigT + (size_t)(col0 + c * 16 + n) * 768 + k0 + Q * 8);
            acc[c] = __builtin_amdgcn_mfma_f32_16x16x32_f16(af, bf, acc[c], 0, 0, 0);
        }
    }
    #pragma unroll
    for (int c = 0; c < 2; ++c) {
        const int col = col0 + c * 16 + n;
        const float bv = bcomb[col];
        #pragma unroll
        for (int r = 0; r < 4; ++r)
            h1[(size_t)(row0 + 4 * Q + r) * 256 + col] = (h16)fmaxf(acc[c][r] + bv, 0.f);
    }
}

// ---------------------------------------------------------------------------
// g2: out(f32) = h1 @ Ws2 + bs2 (B = Ws2T f16). Same shape as g1, K=256.
// ---------------------------------------------------------------------------
__global__ __launch_bounds__(64) void g2_k(
    const h16* __restrict__ h1, const h16* __restrict__ Ws2T,
    const float* __restrict__ bs2, float* __restrict__ out)
{
    const int lane = threadIdx.x, Q = lane >> 4, n = lane & 15;
    const int row0 = (blockIdx.x >> 3) * 16, col0 = (blockIdx.x & 7) * 32;
    const f32x4 z4 = {0.f, 0.f, 0.f, 0.f};
    f32x4 acc[2] = {z4, z4};
    #pragma unroll 4
    for (int k0 = 0; k0 < 256; k0 += 32) {
        h16x8 af = *(const h16x8*)(h1 + (size_t)(row0 + n) * 256 + k0 + Q * 8);
        #pragma unroll
        for (int c = 0; c < 2; ++c) {
            h16x8 bf = *(const h16x8*)(Ws2T + (size_t)(col0 + c * 16 + n) * 256 + k0 + Q * 8);
            acc[c] = __builtin_amdgcn_mfma_f32_16x16x32_f16(af, bf, acc[c], 0, 0, 0);
        }
    }
    #pragma unroll
    for (int c = 0; c < 2; ++c) {
        const int col = col0 + c * 16 + n;
        const float bv = bs2[col];
        #pragma unroll
        for (int r = 0; r < 4; ++r)
            out[(size_t)(row0 + 4 * Q + r) * 256 + col] = acc[c][r] + bv;
    }
}

// ---------------------------------------------------------------------------
extern "C" void kernel_launch(void* const* d_in, const int* in_sizes, int n_in,
                              void* d_out, int out_size, void* d_ws, size_t ws_size,
                              hipStream_t stream)
{
    const float* query = (const float*)d_in[0];
    const float* key   = (const float*)d_in[1];
    const float* value = (const float*)d_in[2];
    const float* dist  = (const float*)d_in[3];
    const int*   mask  = (const int*)d_in[4];
    const float* Wq = (const float*)d_in[5];  const float* bq = (const float*)d_in[6];
    const float* Wk = (const float*)d_in[7];  const float* bk = (const float*)d_in[8];
    const float* Wv = (const float*)d_in[9];  const float* bv = (const float*)d_in[10];
    const float* Wo = (const float*)d_in[11]; const float* bo = (const float*)d_in[12];
    const float* cw1 = (const float*)d_in[13]; const float* cb1 = (const float*)d_in[14];
    const float* cw2 = (const float*)d_in[15]; const float* cb2 = (const float*)d_in[16];
    const float* Ws1 = (const float*)d_in[17]; const float* bs1 = (const float*)d_in[18];
    const float* Ws2 = (const float*)d_in[19]; const float* bs2 = (const float*)d_in[20];

    h16* qb    = (h16*)d_ws;             // 4096x256            (1,048,576)
    h16* kb    = qb + 1048576;           // 4096x256
    h16* vbT   = kb + 1048576;           // 64x32 x 512
    h16* OB    = vbT + 1048576;          // 4096x768            (3,145,728)
    h16* h1    = OB + 3145728;           // 4096x256
    h16* WbigT = h1 + 1048576;           // 256x768             (196,608)
    h16* Ws2T  = WbigT + 196608;         // 256x256             (65,536)
    u16t* fB   = (u16t*)(Ws2T + 65536);  // 64 x 512 x 512      (16,777,216)
    float* bcomb = (float*)(fB + 16777216);  // 256

    k1_k<<<dim3(1905), 256, 0, stream>>>(query, key, value,
                                         Wq, bq, Wk, bk, Wv, bv, Wo, bo,
                                         cw1, cb1, cw2, cb2, Ws1, bs1, Ws2,
                                         dist, mask,
                                         qb, kb, vbT, WbigT, Ws2T, fB, bcomb);

    attn_k<<<dim3(2048), 64, 0, stream>>>(qb, kb, vbT, fB, OB);

    g1_k<<<dim3(2048), 64, 0, stream>>>(OB, WbigT, bcomb, h1);
    g2_k<<<dim3(2048), 64, 0, stream>>>(h1, Ws2T, bs2, (float*)d_out);
}